// Round 4
// baseline (401.025 us; speedup 1.0000x reference)
//
#include <hip/hip_runtime.h>
#include <hip/hip_bf16.h>
#include <cstdint>
#include <cstddef>

#define BATCH 4
#define SEQ   4096
#define EMB   1024
#define M_TOT (BATCH * SEQ)   // 16384
#define KV_CHUNKS 16

using bf16_t = __hip_bfloat16;
typedef __attribute__((ext_vector_type(8))) short bv8;    // 8 bf16 (4 VGPRs)
typedef __attribute__((ext_vector_type(4))) float f32x4;
typedef __attribute__((ext_vector_type(4))) unsigned short us4;  // 4 bf16 (8B)

union SV8 { bv8 v; bf16_t h[8]; };

static __device__ __forceinline__ unsigned short bfbits(float v) {
  bf16_t b = __float2bfloat16(v);
  unsigned short u;
  __builtin_memcpy(&u, &b, 2);
  return u;
}

__device__ __forceinline__ void gload_lds16(const void* g, void* l) {
  __builtin_amdgcn_global_load_lds(
      (const __attribute__((address_space(1))) unsigned int*)g,
      (__attribute__((address_space(3))) unsigned int*)l, 16, 0, 0);
}

#define BAR() asm volatile("s_barrier" ::: "memory")

// ---------- all fp32->bf16 converts in ONE kernel ----------
// blocks [0,8192): x (16.7M elems); [8192,10240): Wq|Wk|Wv -> wqkv, Wo -> wob.
__global__ __launch_bounds__(256) void cvt_all(
    const float* __restrict__ x, const float* __restrict__ wq,
    const float* __restrict__ wk, const float* __restrict__ wv,
    const float* __restrict__ wo, bf16_t* __restrict__ xb,
    bf16_t* __restrict__ wqkv, bf16_t* __restrict__ wob) {
  const int bid = blockIdx.x;
  const float* in;
  bf16_t* out;
  size_t base;
  if (bid < 8192) {
    in = x; out = xb; base = (size_t)bid * 2048;
  } else {
    const int q = (bid - 8192) >> 9, sub = (bid - 8192) & 511;
    base = (size_t)sub * 2048;
    switch (q) {
      case 0:  in = wq; out = wqkv; break;
      case 1:  in = wk; out = wqkv + 1048576; break;
      case 2:  in = wv; out = wqkv + 2097152; break;
      default: in = wo; out = wob; break;
    }
  }
  const size_t i = base + (size_t)threadIdx.x * 8;
  const f32x4 a = *(const f32x4*)(in + i);
  const f32x4 b = *(const f32x4*)(in + i + 4);
  SV8 o;
#pragma unroll
  for (int j = 0; j < 4; ++j) o.h[j] = __float2bfloat16(a[j]);
#pragma unroll
  for (int j = 0; j < 4; ++j) o.h[4 + j] = __float2bfloat16(b[j]);
  *(bv8*)(out + i) = o.v;
}

// ---------- 8-phase 256x256 GEMM, C = A @ W^T (+bias, +opt elu+1) ----------
// Structure identical to round 3 (verified schedule), EXCEPT: MFMA operands
// are swapped -> D = W_tile . A_tile^T = C^T fragments. LDS reads are
// IDENTICAL (fragment-order serves both operand layouts); only the C-store
// changes: lane's 4 regs = 4 consecutive output COLUMNS at one row
// -> coalesced 8B bf16x4 / 16B f32x4 stores (kills the 2.4x HBM write
// amplification of the scalar-scatter epilogue; WRITE_SIZE 232MB -> ~100MB).
template <int VARIANT>  // 0: QKV (N=3072, elu+1 on q,k, bf16 out); 1: N=1024 per-batch W, fp32 out
__global__ __launch_bounds__(512, 2) void gemm8p(
    const bf16_t* __restrict__ A, const bf16_t* __restrict__ Wbase,
    const float* __restrict__ b0, const float* __restrict__ b1,
    const float* __restrict__ b2, void* __restrict__ o0,
    void* __restrict__ o1, void* __restrict__ o2) {
  constexpr int K = 1024;
  constexpr int NT = (VARIANT == 0) ? 12 : 4;
  constexpr int NKT = K / 64;          // 16
  __shared__ char lds[131072];

  const int nwg = NT * 64;             // 768 or 256, %8==0 (bijective swizzle)
  const int wg = (blockIdx.x & 7) * (nwg >> 3) + (blockIdx.x >> 3);
  const int m0 = (wg / NT) * 256;
  const int n0 = (wg % NT) * 256;
  const bf16_t* W = Wbase + (VARIANT ? (size_t)(m0 >> 12) * 1048576ull : 0);
  const int t = threadIdx.x, l = t & 63, w = t >> 6;
  const int wm = w >> 2, wn = w & 3;   // 2(M) x 4(N) wave grid

  // staging map: slot s in [0,1024) of a 16KB half; thread handles s=t, t+512
  const int sr = ((t >> 7) << 4) + (t & 15);
  const int sc = (((t >> 6) & 1) << 5) + (((t >> 4) & 3) << 3);
  const bf16_t* aRow = A + (size_t)(m0 + sr) * K + sc;
  const bf16_t* wRow = W + (size_t)(n0 + sr) * K + sc;
  char* dA = lds + t * 16;
  char* dB = lds + 65536 + t * 16;

  auto ST = [&](int isB, int hf, int kt) {   // stage one 16KB half-tile
    char* d = (isB ? dB : dA) + (kt & 1) * 32768 + hf * 16384;
    const bf16_t* s = (isB ? wRow : aRow) + (size_t)(hf * 128) * K + kt * 64;
    gload_lds16(s, d);
    gload_lds16(s + (size_t)64 * K, d + 8192);
  };

  const char* Ab = lds + wm * 16384 + l * 16;
  const char* Bb = lds + 65536 + (wn >> 1) * 16384 + (wn & 1) * 8192 + l * 16;

  f32x4 acc[8][4] = {};
  bv8 af[4][2], bf[4][2];

  // prologue: K0 complete + K1 B0,B1,A0 (7 halves); keep 3 newest in flight
  ST(1, 0, 0); ST(1, 1, 0); ST(0, 0, 0); ST(0, 1, 0);
  ST(1, 0, 1); ST(1, 1, 1); ST(0, 0, 1);
  asm volatile("s_waitcnt vmcnt(6)" ::: "memory");
  BAR();

#pragma unroll 1
  for (int j = 0; j < NKT; ++j) {
    const int db = (j & 1) * 32768;
    // ---- P1 ----
#pragma unroll
    for (int mb = 0; mb < 4; ++mb)
#pragma unroll
      for (int ks = 0; ks < 2; ++ks)
        af[mb][ks] = *(const bv8*)(Ab + db + mb * 2048 + ks * 1024);
#pragma unroll
    for (int nb = 0; nb < 4; ++nb)
#pragma unroll
      for (int ks = 0; ks < 2; ++ks)
        bf[nb][ks] = *(const bv8*)(Bb + db + nb * 2048 + ks * 1024);
    if (j + 1 < NKT) ST(0, 1, j + 1);
    BAR();
    __builtin_amdgcn_s_setprio(1);
#pragma unroll
    for (int mb = 0; mb < 4; ++mb)
#pragma unroll
      for (int nb = 0; nb < 2; ++nb)
#pragma unroll
        for (int ks = 0; ks < 2; ++ks)
          acc[mb][nb] = __builtin_amdgcn_mfma_f32_16x16x32_bf16(
              bf[nb][ks], af[mb][ks], acc[mb][nb], 0, 0, 0);
    __builtin_amdgcn_s_setprio(0);
    BAR();
    // ---- P2 ----
    if (j + 2 < NKT) ST(1, 0, j + 2);
    BAR();
    __builtin_amdgcn_s_setprio(1);
#pragma unroll
    for (int mb = 0; mb < 4; ++mb)
#pragma unroll
      for (int nb = 2; nb < 4; ++nb)
#pragma unroll
        for (int ks = 0; ks < 2; ++ks)
          acc[mb][nb] = __builtin_amdgcn_mfma_f32_16x16x32_bf16(
              bf[nb][ks], af[mb][ks], acc[mb][nb], 0, 0, 0);
    __builtin_amdgcn_s_setprio(0);
    BAR();
    // ---- P3 ----
#pragma unroll
    for (int mb = 0; mb < 4; ++mb)
#pragma unroll
      for (int ks = 0; ks < 2; ++ks)
        af[mb][ks] = *(const bv8*)(Ab + db + 8192 + mb * 2048 + ks * 1024);
    if (j + 2 < NKT) ST(1, 1, j + 2);
    BAR();
    __builtin_amdgcn_s_setprio(1);
#pragma unroll
    for (int mb = 0; mb < 4; ++mb)
#pragma unroll
      for (int nb = 2; nb < 4; ++nb)
#pragma unroll
        for (int ks = 0; ks < 2; ++ks)
          acc[4 + mb][nb] = __builtin_amdgcn_mfma_f32_16x16x32_bf16(
              bf[nb][ks], af[mb][ks], acc[4 + mb][nb], 0, 0, 0);
    __builtin_amdgcn_s_setprio(0);
    BAR();
    // ---- P4 ----
    if (j + 2 < NKT) {
      ST(0, 0, j + 2);
      asm volatile("s_waitcnt vmcnt(6)" ::: "memory");
    } else if (j == NKT - 2) {
      asm volatile("s_waitcnt vmcnt(0)" ::: "memory");
    }
    BAR();
    __builtin_amdgcn_s_setprio(1);
#pragma unroll
    for (int mb = 0; mb < 4; ++mb)
#pragma unroll
      for (int nb = 0; nb < 2; ++nb)
#pragma unroll
        for (int ks = 0; ks < 2; ++ks)
          acc[4 + mb][nb] = __builtin_amdgcn_mfma_f32_16x16x32_bf16(
              bf[nb][ks], af[mb][ks], acc[4 + mb][nb], 0, 0, 0);
    __builtin_amdgcn_s_setprio(0);
    BAR();
  }

  // epilogue. D = C^T fragments: out row m = rbase + mb*16 + (l&15),
  // out col n = colbase + nb*16 + (l>>4)*4 + r  (r = 4 consecutive cols).
  const int rl = l & 15;
  const int c4 = (l >> 4) << 2;
  const int rbase = m0 + wm * 128;
  if (VARIANT == 0) {
    const int gq = n0 >> 10;  // 0=q, 1=k, 2=v (256-aligned tiles: uniform)
    const float* bias = gq == 0 ? b0 : (gq == 1 ? b1 : b2);
    bf16_t* ob = (bf16_t*)(gq == 0 ? o0 : (gq == 1 ? o1 : o2));
    const int cb = (n0 & 1023) + wn * 64;
#pragma unroll
    for (int nb = 0; nb < 4; ++nb) {
      const int coln = cb + nb * 16 + c4;
      const f32x4 bz = *(const f32x4*)(bias + coln);
#pragma unroll
      for (int mb = 0; mb < 8; ++mb) {
        us4 pk;
#pragma unroll
        for (int r = 0; r < 4; ++r) {
          float v = acc[mb][nb][r] + bz[r];
          if (gq < 2) v = (v > 0.f) ? (v + 1.f) : __expf(v);  // elu(x)+1
          pk[r] = bfbits(v);
        }
        *(us4*)(ob + (size_t)(rbase + mb * 16 + rl) * 1024 + coln) = pk;
      }
    }
  } else {
    const int cb = n0 + wn * 64;
#pragma unroll
    for (int nb = 0; nb < 4; ++nb) {
      const int coln = cb + nb * 16 + c4;
      const f32x4 bz = *(const f32x4*)(b0 + coln);
#pragma unroll
      for (int mb = 0; mb < 8; ++mb) {
        f32x4 ov;
#pragma unroll
        for (int r = 0; r < 4; ++r) ov[r] = acc[mb][nb][r] + bz[r];
        *(f32x4*)((float*)o0 + (size_t)(rbase + mb * 16 + rl) * 1024 + coln) = ov;
      }
    }
  }
}

// ---------- kv partial: pkv[chunk][bh][d][e] = sum_{s in chunk} k[s,d]*v[s,e] ----------
__global__ __launch_bounds__(256) void kv_partial(const bf16_t* __restrict__ Kmat,
                                                  const bf16_t* __restrict__ Vmat,
                                                  float* __restrict__ pkv) {
  const int chunk = blockIdx.x;   // 0..15
  const int bh = blockIdx.y;      // 0..63
  const int b = bh >> 4, h = bh & 15;
  const int t = threadIdx.x;
  __shared__ bf16_t kl[8][64], vl[8][64];
  float acc[16] = {};
  const int e = t & 63, d0 = (t >> 6) * 16;
  const int sl = t >> 5, c2 = (t & 31) * 2;
  const int s0 = chunk * (SEQ / KV_CHUNKS);
  const bf16_t* kp = Kmat + ((size_t)(b * SEQ + s0 + sl)) * EMB + h * 64 + c2;
  const bf16_t* vp = Vmat + ((size_t)(b * SEQ + s0 + sl)) * EMB + h * 64 + c2;
  for (int it = 0; it < (SEQ / KV_CHUNKS) / 8; ++it) {
    const unsigned int kw = *(const unsigned int*)kp;
    const unsigned int vw = *(const unsigned int*)vp;
    __syncthreads();
    *(unsigned int*)&kl[sl][c2] = kw;
    *(unsigned int*)&vl[sl][c2] = vw;
    __syncthreads();
#pragma unroll
    for (int ss = 0; ss < 8; ++ss) {
      const float vv = __bfloat162float(vl[ss][e]);
      SV8 k0, k1;
      k0.v = *(const bv8*)&kl[ss][d0];
      k1.v = *(const bv8*)&kl[ss][d0 + 8];
#pragma unroll
      for (int dd = 0; dd < 8; ++dd) acc[dd] += __bfloat162float(k0.h[dd]) * vv;
#pragma unroll
      for (int dd = 0; dd < 8; ++dd) acc[8 + dd] += __bfloat162float(k1.h[dd]) * vv;
    }
    kp += 8 * EMB;
    vp += 8 * EMB;
  }
  float* outp = pkv + ((size_t)chunk * 64 + bh) * 4096;
#pragma unroll
  for (int dd = 0; dd < 16; ++dd) outp[(d0 + dd) * 64 + e] = acc[dd];
}

// ---------- fold2: reduce pkv over chunks + MT[b][f,h*64+d] = sum_e Wo[f,he]*kv[d][e] ----------
// grid 64 (one block per bh). Reduce kv[64][64] once into an LDS MFMA
// fragment (rows=d, cols=e), then loop 8 Wo f-panels of 128 rows.
// MFMA operands: A = kv-frag (M=d), B = Wo-frag (N=f) -> lane's 4 regs are
// 4 consecutive d-cols of MT at fixed f -> coalesced 8B stores.
__global__ __launch_bounds__(256) void fold2(const float* __restrict__ pkv,
                                             const bf16_t* __restrict__ Wo,
                                             bf16_t* __restrict__ MT) {
  __shared__ char lds[24576];   // kv frag 8KB | Wo panel 16KB
  const int bh = blockIdx.x;
  const int b = bh >> 4, h = bh & 15;
  const int t = threadIdx.x, l = t & 63, w = t >> 6;

  // reduction: thread owns d = t>>2, e in [(t&3)*16, +16)
  const int d = t >> 2, e0 = (t & 3) * 16;
  float s[16] = {};
#pragma unroll
  for (int c = 0; c < KV_CHUNKS; ++c) {
    const float* pp = pkv + ((size_t)c * 64 + bh) * 4096 + d * 64 + e0;
#pragma unroll
    for (int q = 0; q < 4; ++q) {
      const f32x4 v = *(const f32x4*)(pp + q * 4);
#pragma unroll
      for (int r = 0; r < 4; ++r) s[q * 4 + r] += v[r];
    }
  }
  // write as fragment-order bf16: byte(d,e) = (d>>4)*2048 + (e>>5)*1024
  //   + ((e>>3)&3)*256 + (d&15)*16 + (e&7)*2 ; e0 is 8-aligned -> 2x b128
  SV8 p0, p1;
#pragma unroll
  for (int j = 0; j < 8; ++j) p0.h[j] = __float2bfloat16(s[j]);
#pragma unroll
  for (int j = 0; j < 8; ++j) p1.h[j] = __float2bfloat16(s[8 + j]);
  const int fb0 = (d >> 4) * 2048 + (d & 15) * 16;
  *(bv8*)(lds + fb0 + (e0 >> 5) * 1024 + ((e0 >> 3) & 3) * 256) = p0.v;
  const int e1 = e0 + 8;
  *(bv8*)(lds + fb0 + (e1 >> 5) * 1024 + ((e1 >> 3) & 3) * 256) = p1.v;
  __syncthreads();

  bv8 bn[4][2];
#pragma unroll
  for (int db = 0; db < 4; ++db)
#pragma unroll
    for (int ks = 0; ks < 2; ++ks)
      bn[db][ks] = *(const bv8*)(lds + db * 2048 + ks * 1024 + l * 16);

  bf16_t* outB = MT + (size_t)b * 1048576ull + h * 64;
  const int rl = l & 15, c4 = (l >> 4) << 2;
  for (int ft = 0; ft < 8; ++ft) {
    // stage Wo panel [ft*128 .. +128) x [h*64 .. +64) in fragment order
#pragma unroll
    for (int q = 0; q < 4; ++q) {
      const int sslot = q * 256 + t;
      const int row = ((sslot >> 7) << 4) + (sslot & 15);
      const int col = (((sslot >> 6) & 1) << 5) + (((sslot >> 4) & 3) << 3);
      gload_lds16(Wo + (size_t)(ft * 128 + row) * 1024 + h * 64 + col,
                  lds + 8192 + sslot * 16);
    }
    asm volatile("s_waitcnt vmcnt(0)" ::: "memory");
    __syncthreads();
    f32x4 acc[4][2] = {};
    bv8 am[2][2];
#pragma unroll
    for (int i = 0; i < 2; ++i)
#pragma unroll
      for (int ks = 0; ks < 2; ++ks)
        am[i][ks] = *(const bv8*)(lds + 8192 + (w * 2 + i) * 2048 + ks * 1024 + l * 16);
#pragma unroll
    for (int db = 0; db < 4; ++db)
#pragma unroll
      for (int i = 0; i < 2; ++i)
#pragma unroll
        for (int ks = 0; ks < 2; ++ks)
          acc[db][i] = __builtin_amdgcn_mfma_f32_16x16x32_bf16(
              bn[db][ks], am[i][ks], acc[db][i], 0, 0, 0);
#pragma unroll
    for (int i = 0; i < 2; ++i)
#pragma unroll
      for (int db = 0; db < 4; ++db) {
        us4 pk;
#pragma unroll
        for (int r = 0; r < 4; ++r) pk[r] = bfbits(acc[db][i][r]);
        const int f = ft * 128 + w * 32 + i * 16 + rl;
        *(us4*)(outB + (size_t)f * 1024 + db * 16 + c4) = pk;
      }
    __syncthreads();  // all waves done reading Wo panel before next stage
  }
}

extern "C" void kernel_launch(void* const* d_in, const int* in_sizes, int n_in,
                              void* d_out, int out_size, void* d_ws, size_t ws_size,
                              hipStream_t stream) {
  (void)in_sizes; (void)n_in; (void)out_size;
  const float* x  = (const float*)d_in[0];
  const float* Wq = (const float*)d_in[1];
  const float* bq = (const float*)d_in[2];
  const float* Wk = (const float*)d_in[3];
  const float* bk = (const float*)d_in[4];
  const float* Wv = (const float*)d_in[5];
  const float* bv = (const float*)d_in[6];
  const float* Wo = (const float*)d_in[7];
  const float* bo = (const float*)d_in[8];

  // ws (72MB peak): [0,32M) xb, later reused as pkv(16M) | MT(@17M,8M)
  //                 [32M,38M) wqkv | [38M,40M) wob | [40M,72M) q
  // d_out (64MB): k at [0,32M), v at [32M,64M); both dead before the final
  // gemm overwrites d_out with fp32 results.
  const size_t NEED = 72ull * 1024 * 1024;
  if (ws_size < NEED) return;

  char* p = (char*)d_ws;
  bf16_t* xb   = (bf16_t*)p;
  float*  pkv  = (float*)p;                         // aliases xb (x dead)
  bf16_t* MT   = (bf16_t*)(p + 17825792ull);        // 4 x [1024,1024] bf16
  bf16_t* wqkv = (bf16_t*)(p + 33554432ull);        // [3072,1024]
  bf16_t* wob  = (bf16_t*)(p + 39845888ull);
  bf16_t* qb   = (bf16_t*)(p + 41943040ull);

  bf16_t* kb = (bf16_t*)d_out;
  bf16_t* vb = kb + 16777216ull;

  cvt_all<<<10240, 256, 0, stream>>>(x, Wq, Wk, Wv, Wo, xb, wqkv, wob);

  // merged QKV projection: q=elu+1 -> qb(ws), k=elu+1 -> kb(d_out), v -> vb(d_out)
  gemm8p<0><<<768, 512, 0, stream>>>(xb, wqkv, bq, bk, bv, qb, kb, vb);

  kv_partial<<<dim3(KV_CHUNKS, 64), 256, 0, stream>>>(kb, vb, pkv);
  fold2<<<64, 256, 0, stream>>>(pkv, wob, MT);

  // out = q @ MT[b]^T + bo  (fp32 d_out)
  gemm8p<1><<<256, 512, 0, stream>>>(qb, MT, bo, nullptr, nullptr,
                                     d_out, nullptr, nullptr);
}

// Round 5
// 372.350 us; speedup vs baseline: 1.0770x; 1.0770x over previous
//
#include <hip/hip_runtime.h>
#include <hip/hip_bf16.h>
#include <cstdint>
#include <cstddef>

#define BATCH 4
#define SEQ   4096
#define EMB   1024
#define M_TOT (BATCH * SEQ)   // 16384
#define KV_CHUNKS 16

using bf16_t = __hip_bfloat16;
typedef __attribute__((ext_vector_type(8))) short bv8;    // 8 bf16 (4 VGPRs)
typedef __attribute__((ext_vector_type(4))) float f32x4;
typedef __attribute__((ext_vector_type(4))) unsigned short us4;  // 4 bf16 (8B)

union SV8 { bv8 v; bf16_t h[8]; };

static __device__ __forceinline__ unsigned short bfbits(float v) {
  bf16_t b = __float2bfloat16(v);
  unsigned short u;
  __builtin_memcpy(&u, &b, 2);
  return u;
}

__device__ __forceinline__ void gload_lds16(const void* g, void* l) {
  __builtin_amdgcn_global_load_lds(
      (const __attribute__((address_space(1))) unsigned int*)g,
      (__attribute__((address_space(3))) unsigned int*)l, 16, 0, 0);
}

#define BAR() asm volatile("s_barrier" ::: "memory")

// ---------- all fp32->bf16 converts in ONE kernel ----------
__global__ __launch_bounds__(256) void cvt_all(
    const float* __restrict__ x, const float* __restrict__ wq,
    const float* __restrict__ wk, const float* __restrict__ wv,
    const float* __restrict__ wo, bf16_t* __restrict__ xb,
    bf16_t* __restrict__ wqkv, bf16_t* __restrict__ wob) {
  const int bid = blockIdx.x;
  const float* in;
  bf16_t* out;
  size_t base;
  if (bid < 8192) {
    in = x; out = xb; base = (size_t)bid * 2048;
  } else {
    const int q = (bid - 8192) >> 9, sub = (bid - 8192) & 511;
    base = (size_t)sub * 2048;
    switch (q) {
      case 0:  in = wq; out = wqkv; break;
      case 1:  in = wk; out = wqkv + 1048576; break;
      case 2:  in = wv; out = wqkv + 2097152; break;
      default: in = wo; out = wob; break;
    }
  }
  const size_t i = base + (size_t)threadIdx.x * 8;
  const f32x4 a = *(const f32x4*)(in + i);
  const f32x4 b = *(const f32x4*)(in + i + 4);
  SV8 o;
#pragma unroll
  for (int j = 0; j < 4; ++j) o.h[j] = __float2bfloat16(a[j]);
#pragma unroll
  for (int j = 0; j < 4; ++j) o.h[4 + j] = __float2bfloat16(b[j]);
  *(bv8*)(out + i) = o.v;
}

// ---------- persistent 8-phase 256x256 GEMM body ----------
// Same verified per-K-tile schedule as rounds 3/4; NTILES output tiles are
// chained into ONE continuous pipeline with a global K-tile index gkt:
// the (j+1)/(j+2) stage targets simply roll into the next tile's K0/K1, with
// identical slot-deadness and vmcnt(6) ledger proofs. Mid-stream epilogues
// (stores+bias loads) enter the vmcnt ledger as OLDER ops; the next vmcnt(6)
// drains them under the following tile's first phases.
template <int VARIANT, int NTILES>  // VARIANT 0: QKV (NT=12, elu+1 on q,k, bf16); 1: out (NT=4, per-batch W, fp32)
__device__ __forceinline__ void gemm_body(
    const bf16_t* __restrict__ A, const bf16_t* __restrict__ Wbase,
    const float* __restrict__ b0, const float* __restrict__ b1,
    const float* __restrict__ b2, void* __restrict__ o0,
    void* __restrict__ o1, void* __restrict__ o2, char* lds) {
  constexpr int K = 1024;
  constexpr int NT = (VARIANT == 0) ? 12 : 4;
  constexpr int JTOT = NTILES * 16;

  const int nwg = NT * 64 / NTILES;    // 256 in both cases, %8==0
  const int wg = (blockIdx.x & 7) * (nwg >> 3) + (blockIdx.x >> 3);
  const int t = threadIdx.x, l = t & 63, w = t >> 6;
  const int wm = w >> 2, wn = w & 3;

  const int sr = ((t >> 7) << 4) + (t & 15);
  const int sc = (((t >> 6) & 1) << 5) + (((t >> 4) & 3) << 3);
  char* dA = lds + t * 16;
  char* dB = lds + 65536 + t * 16;

  auto ST = [&](int isB, int hf, int gkt) {   // stage one 16KB half-tile
    if (gkt >= JTOT) return;
    const int tau = (NTILES == 1) ? wg : (NTILES * wg + (gkt >> 4));
    const int kt = gkt & 15;
    const int m0s = (tau / NT) * 256, n0s = (tau % NT) * 256;
    const bf16_t* src;
    if (isB) {
      const bf16_t* Wt = Wbase + (VARIANT ? (size_t)(m0s >> 12) * 1048576ull : 0);
      src = Wt + (size_t)(n0s + hf * 128 + sr) * K + kt * 64 + sc;
    } else {
      src = A + (size_t)(m0s + hf * 128 + sr) * K + kt * 64 + sc;
    }
    char* d = (isB ? dB : dA) + (gkt & 1) * 32768 + hf * 16384;
    gload_lds16(src, d);
    gload_lds16(src + (size_t)64 * K, d + 8192);
  };

  const char* Ab = lds + wm * 16384 + l * 16;
  const char* Bb = lds + 65536 + (wn >> 1) * 16384 + (wn & 1) * 8192 + l * 16;

  f32x4 acc[8][4] = {};
  bv8 af[4][2], bf[4][2];

  // prologue: K0 complete + K1 B0,B1,A0 (7 halves); keep 3 newest in flight
  ST(1, 0, 0); ST(1, 1, 0); ST(0, 0, 0); ST(0, 1, 0);
  ST(1, 0, 1); ST(1, 1, 1); ST(0, 0, 1);
  asm volatile("s_waitcnt vmcnt(6)" ::: "memory");
  BAR();

#pragma unroll 1
  for (int tt = 0; tt < NTILES; ++tt) {
    const int tau_c = (NTILES == 1) ? wg : (NTILES * wg + tt);
    const int m0 = (tau_c / NT) * 256, n0 = (tau_c % NT) * 256;

#pragma unroll 1
    for (int j = 0; j < 16; ++j) {
      const int gj = tt * 16 + j;
      const int db = (gj & 1) * 32768;
      // ---- P1 ----
#pragma unroll
      for (int mb = 0; mb < 4; ++mb)
#pragma unroll
        for (int ks = 0; ks < 2; ++ks)
          af[mb][ks] = *(const bv8*)(Ab + db + mb * 2048 + ks * 1024);
#pragma unroll
      for (int nb = 0; nb < 4; ++nb)
#pragma unroll
        for (int ks = 0; ks < 2; ++ks)
          bf[nb][ks] = *(const bv8*)(Bb + db + nb * 2048 + ks * 1024);
      ST(0, 1, gj + 1);
      BAR();
      __builtin_amdgcn_s_setprio(1);
#pragma unroll
      for (int mb = 0; mb < 4; ++mb)
#pragma unroll
        for (int nb = 0; nb < 2; ++nb)
#pragma unroll
          for (int ks = 0; ks < 2; ++ks)
            acc[mb][nb] = __builtin_amdgcn_mfma_f32_16x16x32_bf16(
                bf[nb][ks], af[mb][ks], acc[mb][nb], 0, 0, 0);
      __builtin_amdgcn_s_setprio(0);
      BAR();
      // ---- P2 ----
      ST(1, 0, gj + 2);
      BAR();
      __builtin_amdgcn_s_setprio(1);
#pragma unroll
      for (int mb = 0; mb < 4; ++mb)
#pragma unroll
        for (int nb = 2; nb < 4; ++nb)
#pragma unroll
          for (int ks = 0; ks < 2; ++ks)
            acc[mb][nb] = __builtin_amdgcn_mfma_f32_16x16x32_bf16(
                bf[nb][ks], af[mb][ks], acc[mb][nb], 0, 0, 0);
      __builtin_amdgcn_s_setprio(0);
      BAR();
      // ---- P3 ----
#pragma unroll
      for (int mb = 0; mb < 4; ++mb)
#pragma unroll
        for (int ks = 0; ks < 2; ++ks)
          af[mb][ks] = *(const bv8*)(Ab + db + 8192 + mb * 2048 + ks * 1024);
      ST(1, 1, gj + 2);
      BAR();
      __builtin_amdgcn_s_setprio(1);
#pragma unroll
      for (int mb = 0; mb < 4; ++mb)
#pragma unroll
        for (int nb = 2; nb < 4; ++nb)
#pragma unroll
          for (int ks = 0; ks < 2; ++ks)
            acc[4 + mb][nb] = __builtin_amdgcn_mfma_f32_16x16x32_bf16(
                bf[nb][ks], af[mb][ks], acc[4 + mb][nb], 0, 0, 0);
      __builtin_amdgcn_s_setprio(0);
      BAR();
      // ---- P4 ----
      if (gj + 2 < JTOT) {
        ST(0, 0, gj + 2);
        asm volatile("s_waitcnt vmcnt(6)" ::: "memory");
      } else if (gj == JTOT - 2) {
        asm volatile("s_waitcnt vmcnt(0)" ::: "memory");
      }
      BAR();
      __builtin_amdgcn_s_setprio(1);
#pragma unroll
      for (int mb = 0; mb < 4; ++mb)
#pragma unroll
        for (int nb = 0; nb < 2; ++nb)
#pragma unroll
          for (int ks = 0; ks < 2; ++ks)
            acc[4 + mb][nb] = __builtin_amdgcn_mfma_f32_16x16x32_bf16(
                bf[nb][ks], af[mb][ks], acc[4 + mb][nb], 0, 0, 0);
      __builtin_amdgcn_s_setprio(0);
      BAR();
    }

    // epilogue for tile tau_c. D = C^T frags: row = rbase + mb*16 + (l&15),
    // cols = coln..coln+3. mb-OUTER so each 128B line's pieces are adjacent.
    {
      const int rl = l & 15;
      const int c4 = (l >> 4) << 2;
      const int rbase = m0 + wm * 128;
      if (VARIANT == 0) {
        const int gq = n0 >> 10;  // 0=q, 1=k, 2=v
        const float* bias = gq == 0 ? b0 : (gq == 1 ? b1 : b2);
        bf16_t* ob = (bf16_t*)(gq == 0 ? o0 : (gq == 1 ? o1 : o2));
        const int cb = (n0 & 1023) + wn * 64;
        f32x4 bz[4];
#pragma unroll
        for (int nb = 0; nb < 4; ++nb) bz[nb] = *(const f32x4*)(bias + cb + nb * 16 + c4);
#pragma unroll
        for (int mb = 0; mb < 8; ++mb) {
          const size_t rowoff = (size_t)(rbase + mb * 16 + rl) * 1024;
#pragma unroll
          for (int nb = 0; nb < 4; ++nb) {
            us4 pk;
#pragma unroll
            for (int r = 0; r < 4; ++r) {
              float v = acc[mb][nb][r] + bz[nb][r];
              if (gq < 2) v = (v > 0.f) ? (v + 1.f) : __expf(v);  // elu(x)+1
              pk[r] = bfbits(v);
            }
            *(us4*)(ob + rowoff + cb + nb * 16 + c4) = pk;
          }
        }
      } else {
        const int cb = n0 + wn * 64;
        f32x4 bz[4];
#pragma unroll
        for (int nb = 0; nb < 4; ++nb) bz[nb] = *(const f32x4*)(b0 + cb + nb * 16 + c4);
#pragma unroll
        for (int mb = 0; mb < 8; ++mb) {
          const size_t rowoff = (size_t)(rbase + mb * 16 + rl) * 1024;
#pragma unroll
          for (int nb = 0; nb < 4; ++nb) {
            f32x4 ov;
#pragma unroll
            for (int r = 0; r < 4; ++r) ov[r] = acc[mb][nb][r] + bz[nb][r];
            *(f32x4*)((float*)o0 + rowoff + cb + nb * 16 + c4) = ov;
          }
        }
      }
      if (tt + 1 < NTILES) {
#pragma unroll
        for (int mb = 0; mb < 8; ++mb)
#pragma unroll
          for (int nb = 0; nb < 4; ++nb)
#pragma unroll
            for (int r = 0; r < 4; ++r) acc[mb][nb][r] = 0.f;
      }
    }
  }
}

__global__ __launch_bounds__(512, 2) void gqkv_k(
    const bf16_t* __restrict__ A, const bf16_t* __restrict__ W,
    const float* __restrict__ b0, const float* __restrict__ b1,
    const float* __restrict__ b2, void* o0, void* o1, void* o2) {
  __shared__ char lds[131072];
  gemm_body<0, 3>(A, W, b0, b1, b2, o0, o1, o2, lds);
}

__global__ __launch_bounds__(512, 2) void gout_k(
    const bf16_t* __restrict__ A, const bf16_t* __restrict__ W,
    const float* __restrict__ b0, void* o0) {
  __shared__ char lds[131072];
  gemm_body<1, 1>(A, W, b0, nullptr, nullptr, o0, nullptr, nullptr, lds);
}

// ---------- kv partial: pkv[chunk][bh][d][e] = sum_{s in chunk} k[s,d]*v[s,e] ----------
__global__ __launch_bounds__(256) void kv_partial(const bf16_t* __restrict__ Kmat,
                                                  const bf16_t* __restrict__ Vmat,
                                                  float* __restrict__ pkv) {
  const int chunk = blockIdx.x;   // 0..15
  const int bh = blockIdx.y;      // 0..63
  const int b = bh >> 4, h = bh & 15;
  const int t = threadIdx.x;
  __shared__ bf16_t kl[8][64], vl[8][64];
  float acc[16] = {};
  const int e = t & 63, d0 = (t >> 6) * 16;
  const int sl = t >> 5, c2 = (t & 31) * 2;
  const int s0 = chunk * (SEQ / KV_CHUNKS);
  const bf16_t* kp = Kmat + ((size_t)(b * SEQ + s0 + sl)) * EMB + h * 64 + c2;
  const bf16_t* vp = Vmat + ((size_t)(b * SEQ + s0 + sl)) * EMB + h * 64 + c2;
  for (int it = 0; it < (SEQ / KV_CHUNKS) / 8; ++it) {
    const unsigned int kw = *(const unsigned int*)kp;
    const unsigned int vw = *(const unsigned int*)vp;
    __syncthreads();
    *(unsigned int*)&kl[sl][c2] = kw;
    *(unsigned int*)&vl[sl][c2] = vw;
    __syncthreads();
#pragma unroll
    for (int ss = 0; ss < 8; ++ss) {
      const float vv = __bfloat162float(vl[ss][e]);
      SV8 k0, k1;
      k0.v = *(const bv8*)&kl[ss][d0];
      k1.v = *(const bv8*)&kl[ss][d0 + 8];
#pragma unroll
      for (int dd = 0; dd < 8; ++dd) acc[dd] += __bfloat162float(k0.h[dd]) * vv;
#pragma unroll
      for (int dd = 0; dd < 8; ++dd) acc[8 + dd] += __bfloat162float(k1.h[dd]) * vv;
    }
    kp += 8 * EMB;
    vp += 8 * EMB;
  }
  float* outp = pkv + ((size_t)chunk * 64 + bh) * 4096;
#pragma unroll
  for (int dd = 0; dd < 16; ++dd) outp[(d0 + dd) * 64 + e] = acc[dd];
}

// ---------- fold2: reduce pkv + MT[b][f,h*64+d] = sum_e Wo[f,he]*kv[d][e] ----------
__global__ __launch_bounds__(256) void fold2(const float* __restrict__ pkv,
                                             const bf16_t* __restrict__ Wo,
                                             bf16_t* __restrict__ MT) {
  __shared__ char lds[24576];   // kv frag 8KB | Wo panel 16KB
  const int bh = blockIdx.x;
  const int b = bh >> 4, h = bh & 15;
  const int t = threadIdx.x, l = t & 63, w = t >> 6;

  const int d = t >> 2, e0 = (t & 3) * 16;
  float s[16] = {};
#pragma unroll
  for (int c = 0; c < KV_CHUNKS; ++c) {
    const float* pp = pkv + ((size_t)c * 64 + bh) * 4096 + d * 64 + e0;
#pragma unroll
    for (int q = 0; q < 4; ++q) {
      const f32x4 v = *(const f32x4*)(pp + q * 4);
#pragma unroll
      for (int r = 0; r < 4; ++r) s[q * 4 + r] += v[r];
    }
  }
  SV8 p0, p1;
#pragma unroll
  for (int j = 0; j < 8; ++j) p0.h[j] = __float2bfloat16(s[j]);
#pragma unroll
  for (int j = 0; j < 8; ++j) p1.h[j] = __float2bfloat16(s[8 + j]);
  const int fb0 = (d >> 4) * 2048 + (d & 15) * 16;
  *(bv8*)(lds + fb0 + (e0 >> 5) * 1024 + ((e0 >> 3) & 3) * 256) = p0.v;
  const int e1 = e0 + 8;
  *(bv8*)(lds + fb0 + (e1 >> 5) * 1024 + ((e1 >> 3) & 3) * 256) = p1.v;
  __syncthreads();

  bv8 bn[4][2];
#pragma unroll
  for (int db = 0; db < 4; ++db)
#pragma unroll
    for (int ks = 0; ks < 2; ++ks)
      bn[db][ks] = *(const bv8*)(lds + db * 2048 + ks * 1024 + l * 16);

  bf16_t* outB = MT + (size_t)b * 1048576ull + h * 64;
  const int rl = l & 15, c4 = (l >> 4) << 2;
  for (int ft = 0; ft < 8; ++ft) {
#pragma unroll
    for (int q = 0; q < 4; ++q) {
      const int sslot = q * 256 + t;
      const int row = ((sslot >> 7) << 4) + (sslot & 15);
      const int col = (((sslot >> 6) & 1) << 5) + (((sslot >> 4) & 3) << 3);
      gload_lds16(Wo + (size_t)(ft * 128 + row) * 1024 + h * 64 + col,
                  lds + 8192 + sslot * 16);
    }
    asm volatile("s_waitcnt vmcnt(0)" ::: "memory");
    __syncthreads();
    f32x4 acc[4][2] = {};
    bv8 am[2][2];
#pragma unroll
    for (int i = 0; i < 2; ++i)
#pragma unroll
      for (int ks = 0; ks < 2; ++ks)
        am[i][ks] = *(const bv8*)(lds + 8192 + (w * 2 + i) * 2048 + ks * 1024 + l * 16);
#pragma unroll
    for (int db = 0; db < 4; ++db)
#pragma unroll
      for (int i = 0; i < 2; ++i)
#pragma unroll
        for (int ks = 0; ks < 2; ++ks)
          acc[db][i] = __builtin_amdgcn_mfma_f32_16x16x32_bf16(
              bn[db][ks], am[i][ks], acc[db][i], 0, 0, 0);
#pragma unroll
    for (int i = 0; i < 2; ++i)
#pragma unroll
      for (int db = 0; db < 4; ++db) {
        us4 pk;
#pragma unroll
        for (int r = 0; r < 4; ++r) pk[r] = bfbits(acc[db][i][r]);
        const int f = ft * 128 + w * 32 + i * 16 + rl;
        *(us4*)(outB + (size_t)f * 1024 + db * 16 + c4) = pk;
      }
    __syncthreads();
  }
}

extern "C" void kernel_launch(void* const* d_in, const int* in_sizes, int n_in,
                              void* d_out, int out_size, void* d_ws, size_t ws_size,
                              hipStream_t stream) {
  (void)in_sizes; (void)n_in; (void)out_size;
  const float* x  = (const float*)d_in[0];
  const float* Wq = (const float*)d_in[1];
  const float* bq = (const float*)d_in[2];
  const float* Wk = (const float*)d_in[3];
  const float* bk = (const float*)d_in[4];
  const float* Wv = (const float*)d_in[5];
  const float* bv = (const float*)d_in[6];
  const float* Wo = (const float*)d_in[7];
  const float* bo = (const float*)d_in[8];

  // ws (72MB peak): [0,32M) xb, later reused as pkv(16M) | MT(@17M,8M)
  //                 [32M,38M) wqkv | [38M,40M) wob | [40M,72M) q
  // d_out (64MB): k at [0,32M), v at [32M,64M); both dead before gout_k
  // overwrites d_out with fp32 results.
  const size_t NEED = 72ull * 1024 * 1024;
  if (ws_size < NEED) return;

  char* p = (char*)d_ws;
  bf16_t* xb   = (bf16_t*)p;
  float*  pkv  = (float*)p;                         // aliases xb (x dead)
  bf16_t* MT   = (bf16_t*)(p + 17825792ull);        // 4 x [1024,1024] bf16
  bf16_t* wqkv = (bf16_t*)(p + 33554432ull);        // [3072,1024]
  bf16_t* wob  = (bf16_t*)(p + 39845888ull);
  bf16_t* qb   = (bf16_t*)(p + 41943040ull);

  bf16_t* kb = (bf16_t*)d_out;
  bf16_t* vb = kb + 16777216ull;

  cvt_all<<<10240, 256, 0, stream>>>(x, Wq, Wk, Wv, Wo, xb, wqkv, wob);

  // merged persistent QKV projection: q=elu+1 -> qb(ws), k -> kb, v -> vb
  gqkv_k<<<256, 512, 0, stream>>>(xb, wqkv, bq, bk, bv, qb, kb, vb);

  kv_partial<<<dim3(KV_CHUNKS, 64), 256, 0, stream>>>(kb, vb, pkv);
  fold2<<<64, 256, 0, stream>>>(pkv, wob, MT);

  // out = q @ MT[b]^T + bo  (fp32 d_out)
  gout_k<<<256, 512, 0, stream>>>(qb, MT, bo, d_out);
}